// Round 5
// baseline (465.694 us; speedup 1.0000x reference)
//
#include <hip/hip_runtime.h>

// LSTM via split-bf16 MFMA, round 5. B=4096, T=512, I=10, H=32, O=1.
// R3/R4 were latency-bound at 1 wave/SIMD (~1600 cyc/step): quarter-rate
// transcendentals (24/wave/step x 8 cyc), 6-deep MFMA chains, ds_read
// latency, barrier -- all serially exposed with no second wave to fill
// bubbles. R5: 8-wave blocks (512 thr), 256 blocks = 2 waves/SIMD. Waves
// w and w+4 duplicate the (cheap, 10%-utilized) MFMA chain but SPLIT the
// expensive activation loop: wave w does C-rows r={0,1} (batches 4q+0,1),
// wave w+4 does r={2,3}. Trans ops per wave halve (24->12); the twin wave
// fills latency bubbles.
//
// Layout (unchanged, verified absmax 2e-3):
//   wave slice ws=wv&3 owns hidden [8ws, 8ws+8) as 2 N-tiles of
//   mfma_f32_16x16x32_bf16: tile0 = [i | f], tile1 = [g | o].
//   C: col=lane&15 (gate col), row=quad*4+reg (batch).
//   A: A[m=lane&15 (batch)][k=quad*8+j].
//   h exchanged as bf16 hi/lo planes in A-frag order, stride 40 (2-way banks,
//   free). ds_write_b16 by writer, 2x ds_read_b128 by reader, zero perms.

#define T_SZ 512
#define I_SZ 10
#define H_SZ 32
#define HSTR 40   // bf16 stride per batch row (80 B)

typedef short bf16x8 __attribute__((ext_vector_type(8)));
typedef float f32x4  __attribute__((ext_vector_type(4)));
typedef int   i32x4  __attribute__((ext_vector_type(4)));

union FB { i32x4 i; bf16x8 b; };
static __device__ __forceinline__ bf16x8 fragv(i32x4 v) { FB u; u.i = v; return u.b; }
static __device__ __forceinline__ bf16x8 frag4(int a, int b, int c, int d) {
    FB u; u.i = (i32x4){a, b, c, d}; return u.b;
}

// low16 = top16(e), high16 = top16(o)
static __device__ __forceinline__ int pack_hi16(float o, float e) {
    return (int)__builtin_amdgcn_perm(__float_as_uint(o), __float_as_uint(e), 0x07060302u);
}

static __device__ __forceinline__ void split8(const float w[8], int hi[4], int lo[4]) {
    #pragma unroll
    for (int j = 0; j < 4; ++j) {
        float e = w[2*j], o = w[2*j+1];
        float eh = __uint_as_float(__float_as_uint(e) & 0xFFFF0000u);
        float oh = __uint_as_float(__float_as_uint(o) & 0xFFFF0000u);
        hi[j] = pack_hi16(o, e);
        lo[j] = pack_hi16(o - oh, e - eh);
    }
}

static __device__ __forceinline__ float dpp_ror8(float v) {
    return __int_as_float(__builtin_amdgcn_mov_dpp(__float_as_int(v), 0x128, 0xF, 0xF, true));
}

#define MFMA(A, B, C) __builtin_amdgcn_mfma_f32_16x16x32_bf16((A), (B), (C), 0, 0, 0)

__global__ __launch_bounds__(512, 2)
void lstm_mfma(const float* __restrict__ x, const float* __restrict__ W_ih,
               const float* __restrict__ W_hh, const float* __restrict__ b_ih,
               const float* __restrict__ b_hh, const float* __restrict__ W_dense,
               const float* __restrict__ b_dense, float* __restrict__ out)
{
    const int tid   = threadIdx.x;          // 0..511
    const int wv    = tid >> 6;             // 0..7
    const int ws    = wv & 3;               // hidden slice
    const int ph    = wv >> 2;              // pair half: 0 -> r={0,1}, 1 -> r={2,3}
    const int lane  = tid & 63;
    const int col   = lane & 15;
    const int quad  = lane >> 4;
    const int bbase = blockIdx.x * 16;

    const int  jloc = col & 7;
    const int  hid  = 8 * ws + jloc;
    const bool isA  = (col < 8);
    const int  row0 = (isA ? 0 : 32) + hid;    // i | f
    const int  row1 = (isA ? 64 : 96) + hid;   // g | o

    // ---- weight B-fragments (one-time; duplicated across pair halves) ----
    int bhh0h[4], bhh0l[4], bhh1h[4], bhh1l[4];
    {
        float w[8];
        const float* p = W_hh + row0 * H_SZ + 8 * quad;
        #pragma unroll
        for (int j = 0; j < 4; ++j) { float2 v = *(const float2*)(p + 2*j); w[2*j] = v.x; w[2*j+1] = v.y; }
        split8(w, bhh0h, bhh0l);
        p = W_hh + row1 * H_SZ + 8 * quad;
        #pragma unroll
        for (int j = 0; j < 4; ++j) { float2 v = *(const float2*)(p + 2*j); w[2*j] = v.x; w[2*j+1] = v.y; }
        split8(w, bhh1h, bhh1l);
    }
    int bih0h[4], bih0l[4], bih1h[4], bih1l[4];
    {
        float w[8];
        #pragma unroll
        for (int j = 0; j < 8; ++j) w[j] = 0.0f;
        if (quad == 0) {
            const float* p = W_ih + row0 * I_SZ;
            #pragma unroll
            for (int j = 0; j < 4; ++j) { float2 v = *(const float2*)(p + 2*j); w[2*j] = v.x; w[2*j+1] = v.y; }
        } else if (quad == 1) {
            float2 v = *(const float2*)(W_ih + row0 * I_SZ + 8); w[0] = v.x; w[1] = v.y;
        }
        split8(w, bih0h, bih0l);
        #pragma unroll
        for (int j = 0; j < 8; ++j) w[j] = 0.0f;
        if (quad == 0) {
            const float* p = W_ih + row1 * I_SZ;
            #pragma unroll
            for (int j = 0; j < 4; ++j) { float2 v = *(const float2*)(p + 2*j); w[2*j] = v.x; w[2*j+1] = v.y; }
        } else if (quad == 1) {
            float2 v = *(const float2*)(W_ih + row1 * I_SZ + 8); w[0] = v.x; w[1] = v.y;
        }
        split8(w, bih1h, bih1l);
    }

    const float bias0  = b_ih[row0] + b_hh[row0];
    const float bias1  = b_ih[row1] + b_hh[row1];
    const f32x4 biasv0 = {bias0, bias0, bias0, bias0};
    const f32x4 biasv1 = {bias1, bias1, bias1, bias1};

    // ---- LDS h planes: bf16 hi/lo, A-frag order ----
    __shared__ __attribute__((aligned(16))) short sh_hi[2][16 * HSTR];
    __shared__ __attribute__((aligned(16))) short sh_lo[2][16 * HSTR];
    {
        int* z0 = (int*)&sh_hi[0][0];
        int* z1 = (int*)&sh_lo[0][0];
        #pragma unroll
        for (int i = 0; i < (16 * HSTR + 511) / 512; ++i) {   // 2 bufs * 16*40 shorts = 640 ints
            int idx = tid + i * 512;
            if (idx < 16 * HSTR) { z0[idx] = 0; z1[idx] = 0; }
        }
    }
    __syncthreads();

    // ---- per-lane activation constants ----
    const float m1 = isA ? -2.8853901f : -1.4426950f;   // exp2 scale (tanh|sigm)
    const float sc = isA ?  2.0f : 1.0f;
    const float so = isA ? -1.0f : 0.0f;
    const float nL = -1.4426950f;                        // -log2(e)

    // ---- x stream (batch = col; address uniform across quads -> coalesced) ----
    const float* xrow = x + (size_t)(bbase + col) * (T_SZ * I_SZ);
    float2 xc0 = *(const float2*)(xrow + 0);
    float2 xc1 = *(const float2*)(xrow + 2);
    float2 xc2 = *(const float2*)(xrow + 4);
    float2 xc3 = *(const float2*)(xrow + 6);
    float2 xc4 = *(const float2*)(xrow + 8);

    float c0 = 0.0f, c1 = 0.0f;            // this wave's two C-rows (r = 2*ph + {0,1})
    const bool q0 = (quad == 0), q1 = (quad == 1);
    const int  rA = 2 * ph;                // first owned row
    // LDS write offsets for the two owned batch rows (isA lanes only)
    const int wo0 = (4 * quad + rA)     * HSTR + hid;
    const int wo1 = (4 * quad + rA + 1) * HSTR + hid;

    #pragma unroll 2
    for (int t = 0; t < T_SZ; ++t) {
        const int rb = t & 1;
        const int wb = rb ^ 1;

        // h fragment reads (issue first; consumed after x-chain)
        const short* hp = &sh_hi[rb][col * HSTR + 8 * quad];
        const short* lp = &sh_lo[rb][col * HSTR + 8 * quad];
        i32x4 hhi_ = *(const i32x4*)hp;
        i32x4 hlo_ = *(const i32x4*)lp;

        // pack current x to bf16 A-frag (quad0: k0..7, quad1: k8,9)
        int p0 = pack_hi16(xc0.y, xc0.x);
        int p1 = pack_hi16(xc1.y, xc1.x);
        int p2 = pack_hi16(xc2.y, xc2.x);
        int p3 = pack_hi16(xc3.y, xc3.x);
        int p4 = pack_hi16(xc4.y, xc4.x);
        bf16x8 xf = frag4(q0 ? p0 : (q1 ? p4 : 0),
                          q0 ? p1 : 0, q0 ? p2 : 0, q0 ? p3 : 0);

        // prefetch next x
        if (t + 1 < T_SZ) {
            const float* xr = xrow + (t + 1) * I_SZ;
            xc0 = *(const float2*)(xr + 0);
            xc1 = *(const float2*)(xr + 2);
            xc2 = *(const float2*)(xr + 4);
            xc3 = *(const float2*)(xr + 6);
            xc4 = *(const float2*)(xr + 8);
        }

        // x-part (independent of h, overlaps ds_read latency)
        f32x4 a0 = MFMA(xf, frag4(bih0h[0], bih0h[1], bih0h[2], bih0h[3]), biasv0);
        f32x4 a1 = MFMA(xf, frag4(bih1h[0], bih1h[1], bih1h[2], bih1h[3]), biasv1);
        a0 = MFMA(xf, frag4(bih0l[0], bih0l[1], bih0l[2], bih0l[3]), a0);
        a1 = MFMA(xf, frag4(bih1l[0], bih1l[1], bih1l[2], bih1l[3]), a1);

        // h-part, 3-term split: Whi*hhi + Whi*hlo + Wlo*hhi
        bf16x8 hhi = fragv(hhi_), hlo = fragv(hlo_);
        a0 = MFMA(hhi, frag4(bhh0h[0], bhh0h[1], bhh0h[2], bhh0h[3]), a0);
        a1 = MFMA(hhi, frag4(bhh1h[0], bhh1h[1], bhh1h[2], bhh1h[3]), a1);
        a0 = MFMA(hlo, frag4(bhh0h[0], bhh0h[1], bhh0h[2], bhh0h[3]), a0);
        a1 = MFMA(hlo, frag4(bhh1h[0], bhh1h[1], bhh1h[2], bhh1h[3]), a1);
        a0 = MFMA(hhi, frag4(bhh0l[0], bhh0l[1], bhh0l[2], bhh0l[3]), a0);
        a1 = MFMA(hhi, frag4(bhh1l[0], bhh1l[1], bhh1l[2], bhh1l[3]), a1);

        // this wave's two C-rows (pair-half split: ph=0 -> regs 0,1; ph=1 -> 2,3)
        float pa0 = ph ? a0[2] : a0[0];
        float pa1 = ph ? a0[3] : a0[1];
        float pb0 = ph ? a1[2] : a1[0];
        float pb1 = ph ? a1[3] : a1[1];

        // activations + state + h store for the 2 owned rows
        {   // row rA (batch 4q + rA)
            float s0 = __builtin_amdgcn_rcpf(1.0f + __builtin_amdgcn_exp2f(nL * pa0));
            float rr = __builtin_amdgcn_rcpf(1.0f + __builtin_amdgcn_exp2f(m1 * pb0));
            float s1 = fmaf(sc, rr, so);
            float fg = dpp_ror8(s0);
            float og = dpp_ror8(s1);
            float cn = fmaf(fg, c0, s0 * s1);
            c0 = cn;
            float tr = __builtin_amdgcn_rcpf(1.0f + __builtin_amdgcn_exp2f(-2.8853901f * cn));
            float h  = fmaf(og + og, tr, -og);
            if (isA) {
                unsigned hb  = __float_as_uint(h);
                float    hif = __uint_as_float(hb & 0xFFFF0000u);
                float    lo  = h - hif;
                sh_hi[wb][wo0] = (short)(hb >> 16);
                sh_lo[wb][wo0] = (short)(__float_as_uint(lo) >> 16);
            }
        }
        {   // row rA+1 (batch 4q + rA + 1)
            float s0 = __builtin_amdgcn_rcpf(1.0f + __builtin_amdgcn_exp2f(nL * pa1));
            float rr = __builtin_amdgcn_rcpf(1.0f + __builtin_amdgcn_exp2f(m1 * pb1));
            float s1 = fmaf(sc, rr, so);
            float fg = dpp_ror8(s0);
            float og = dpp_ror8(s1);
            float cn = fmaf(fg, c1, s0 * s1);
            c1 = cn;
            float tr = __builtin_amdgcn_rcpf(1.0f + __builtin_amdgcn_exp2f(-2.8853901f * cn));
            float h  = fmaf(og + og, tr, -og);
            if (isA) {
                unsigned hb  = __float_as_uint(h);
                float    hif = __uint_as_float(hb & 0xFFFF0000u);
                float    lo  = h - hif;
                sh_hi[wb][wo1] = (short)(hb >> 16);
                sh_lo[wb][wo1] = (short)(__float_as_uint(lo) >> 16);
            }
        }
        __syncthreads();
    }

    // ---- dense head: final h in buffer 0 (T even) ----
    if (wv == 0 && lane < 16) {
        float acc = b_dense[0];
        #pragma unroll 4
        for (int j = 0; j < H_SZ; ++j) {
            unsigned hi = (unsigned short)sh_hi[0][lane * HSTR + j];
            unsigned lo = (unsigned short)sh_lo[0][lane * HSTR + j];
            float hv = __uint_as_float(hi << 16) + __uint_as_float(lo << 16);
            acc += hv * W_dense[j];
        }
        out[bbase + lane] = acc;
    }
}

extern "C" void kernel_launch(void* const* d_in, const int* in_sizes, int n_in,
                              void* d_out, int out_size, void* d_ws, size_t ws_size,
                              hipStream_t stream) {
    const float* x       = (const float*)d_in[0];
    const float* W_ih    = (const float*)d_in[1];
    const float* W_hh    = (const float*)d_in[2];
    const float* b_ih    = (const float*)d_in[3];
    const float* b_hh    = (const float*)d_in[4];
    const float* W_dense = (const float*)d_in[5];
    const float* b_dense = (const float*)d_in[6];
    float* out = (float*)d_out;

    // 256 blocks x 8 waves (512 thr) = 2048 waves = 2 waves/SIMD; 16 batches/block
    lstm_mfma<<<dim3(256), dim3(512), 0, stream>>>(
        x, W_ih, W_hh, b_ih, b_hh, W_dense, b_dense, out);
}

// Round 7
// 450.928 us; speedup vs baseline: 1.0327x; 1.0327x over previous
//
#include <hip/hip_runtime.h>

// LSTM via fp16-split MFMA, round 7 (= R6 + compile fix: cvt_pkrtz returns
// __fp16x2, not _Float16x2). B=4096, T=512, I=10, H=32, O=1.
// R5 lesson: same-block waves share the per-step barrier -> no mutual stall
// hiding. R6/7: 512 blocks x 4 waves, M=8 batches/block -> 2 INDEPENDENT
// blocks/CU whose barriers are uncorrelated; one block's waves issue while
// the other sleeps. MFMA rows 8..15 are ghosts (zero h, dup x) -- MFMA pipe
// is ~10% utilized so wasting half a tile is free.
// Numerics: fp16 (11 mantissa bits) 2-term split: preact = Whi*x_hat +
// Whi*hhi + Whi*hlo, all fp32-accumulated. Error ~2^-11 relative -- better
// than the verified bf16 3-term (absmax 2e-3) at 6 MFMAs/step (was 10) and
// a 3-deep (was 6-deep) dependent MFMA chain.
//
// Layout per block: wave ws owns hidden slice [8ws, 8ws+8) as 2 N-tiles of
// mfma_f32_16x16x32_f16: tile0 = [i_hid | f_hid], tile1 = [g_hid | o_hid].
// C: col=lane&15 (gate col), row=quad*4+reg (batch; rows 8-15 ghost).
// A: A[m=lane&15 (batch)][k=quad*8+j] (m=8-15 ghost rows read zero h).
// h exchange: fp16 hi/lo planes in A-frag order, stride 40 (2-way banks,
// free), ping-pong buffers, one __syncthreads per step.
// x: 2-step prefetch (two register sets, unroll 2) so HBM-miss latency
// (~900 cyc) stays covered when the step shrinks.

#define T_SZ 512
#define I_SZ 10
#define H_SZ 32
#define HSTR 40   // fp16 stride per batch row (80 B)

typedef _Float16 half8  __attribute__((ext_vector_type(8)));
typedef __fp16   fp16x2 __attribute__((ext_vector_type(2)));
typedef float    f32x4  __attribute__((ext_vector_type(4)));
typedef int      i32x4  __attribute__((ext_vector_type(4)));

union FH { i32x4 i; half8 h; };
static __device__ __forceinline__ half8 fragv(i32x4 v) { FH u; u.i = v; return u.h; }
static __device__ __forceinline__ half8 frag4(int a, int b, int c, int d) {
    FH u; u.i = (i32x4){a, b, c, d}; return u.h;
}

// pack 2 fp32 -> 2 fp16 in one dword: low = lo, high = hi (v_cvt_pkrtz_f16_f32)
static __device__ __forceinline__ int pk16(float lo, float hi) {
    union { fp16x2 h; int i; } u;
    u.h = __builtin_amdgcn_cvt_pkrtz(lo, hi);
    return u.i;
}

static __device__ __forceinline__ float dpp_ror8(float v) {
    // 16-lane row rotate by 8: lane c receives lane (c+8)&15 (partner gate col)
    return __int_as_float(__builtin_amdgcn_mov_dpp(__float_as_int(v), 0x128, 0xF, 0xF, true));
}

#define MFMAH(A, B, C) __builtin_amdgcn_mfma_f32_16x16x32_f16((A), (B), (C), 0, 0, 0)

__global__ __launch_bounds__(256, 2)
void lstm_mfma(const float* __restrict__ x, const float* __restrict__ W_ih,
               const float* __restrict__ W_hh, const float* __restrict__ b_ih,
               const float* __restrict__ b_hh, const float* __restrict__ W_dense,
               const float* __restrict__ b_dense, float* __restrict__ out)
{
    const int tid   = threadIdx.x;          // 0..255
    const int ws    = tid >> 6;             // wave = hidden slice 0..3
    const int lane  = tid & 63;
    const int col   = lane & 15;
    const int quad  = lane >> 4;
    const int bbase = blockIdx.x * 8;       // 512 blocks x 8 batches

    const int  jloc = col & 7;
    const int  hid  = 8 * ws + jloc;
    const bool isA  = (col < 8);
    const int  row0 = (isA ? 0 : 32) + hid;    // i | f
    const int  row1 = (isA ? 64 : 96) + hid;   // g | o

    // ---- fp16 weight B-fragments (1-term W), built once ----
    int bh0[4], bh1[4];
    {
        const float* p = W_hh + row0 * H_SZ + 8 * quad;
        #pragma unroll
        for (int j = 0; j < 4; ++j) { float2 v = *(const float2*)(p + 2*j); bh0[j] = pk16(v.x, v.y); }
        p = W_hh + row1 * H_SZ + 8 * quad;
        #pragma unroll
        for (int j = 0; j < 4; ++j) { float2 v = *(const float2*)(p + 2*j); bh1[j] = pk16(v.x, v.y); }
    }
    int bi0[4] = {0, 0, 0, 0}, bi1[4] = {0, 0, 0, 0};
    if (quad == 0) {
        const float* p = W_ih + row0 * I_SZ;
        #pragma unroll
        for (int j = 0; j < 4; ++j) { float2 v = *(const float2*)(p + 2*j); bi0[j] = pk16(v.x, v.y); }
        p = W_ih + row1 * I_SZ;
        #pragma unroll
        for (int j = 0; j < 4; ++j) { float2 v = *(const float2*)(p + 2*j); bi1[j] = pk16(v.x, v.y); }
    } else if (quad == 1) {
        float2 v = *(const float2*)(W_ih + row0 * I_SZ + 8); bi0[0] = pk16(v.x, v.y);
        v = *(const float2*)(W_ih + row1 * I_SZ + 8);        bi1[0] = pk16(v.x, v.y);
    }

    const float bias0  = b_ih[row0] + b_hh[row0];
    const float bias1  = b_ih[row1] + b_hh[row1];
    const f32x4 biasv0 = {bias0, bias0, bias0, bias0};
    const f32x4 biasv1 = {bias1, bias1, bias1, bias1};

    // ---- LDS h planes (fp16 hi/lo, A-frag order); rows 8-15 stay zero ----
    __shared__ __attribute__((aligned(16))) _Float16 sh_hi[2][16 * HSTR];
    __shared__ __attribute__((aligned(16))) _Float16 sh_lo[2][16 * HSTR];
    {
        int* z0 = (int*)&sh_hi[0][0];
        int* z1 = (int*)&sh_lo[0][0];
        #pragma unroll
        for (int i = 0; i < (16 * HSTR + 255) / 256; ++i) {   // 2*16*40 halves = 640 ints
            int idx = tid + i * 256;
            if (idx < 16 * HSTR) { z0[idx] = 0; z1[idx] = 0; }
        }
    }
    __syncthreads();

    // ---- per-lane activation constants ----
    const float m1 = isA ? -2.8853901f : -1.4426950f;   // exp2 scale (tanh|sigm)
    const float sc = isA ?  2.0f : 1.0f;
    const float so = isA ? -1.0f : 0.0f;
    const float nL = -1.4426950f;                        // -log2(e)

    // ---- x stream: batch = bbase + (col&7); 2-deep prefetch (sets a,b) ----
    const float* xrow = x + (size_t)(bbase + (col & 7)) * (T_SZ * I_SZ);
    float2 xa0 = *(const float2*)(xrow + 0), xa1 = *(const float2*)(xrow + 2),
           xa2 = *(const float2*)(xrow + 4), xa3 = *(const float2*)(xrow + 6),
           xa4 = *(const float2*)(xrow + 8);
    float2 xb0 = *(const float2*)(xrow + I_SZ + 0), xb1 = *(const float2*)(xrow + I_SZ + 2),
           xb2 = *(const float2*)(xrow + I_SZ + 4), xb3 = *(const float2*)(xrow + I_SZ + 6),
           xb4 = *(const float2*)(xrow + I_SZ + 8);

    float c0 = 0.f, c1 = 0.f, c2 = 0.f, c3 = 0.f;
    const bool q0 = (quad == 0), q1 = (quad == 1);
    const bool wr = isA && (quad < 2);      // writer lanes (real batches 0..7)

    for (int t = 0; t < T_SZ; t += 2) {
        #pragma unroll
        for (int u = 0; u < 2; ++u) {
            const int rb = u, wb = u ^ 1;

            // h fragments (issue first; waitcnt lands before first h-MFMA)
            const _Float16* hp = &sh_hi[rb][col * HSTR + 8 * quad];
            const _Float16* lp = &sh_lo[rb][col * HSTR + 8 * quad];
            i32x4 hhi_ = *(const i32x4*)hp;
            i32x4 hlo_ = *(const i32x4*)lp;

            // pack current x set to fp16 A-frag (quad0: k0-7, quad1: k8,9)
            float2 y0 = u ? xb0 : xa0, y1 = u ? xb1 : xa1, y2 = u ? xb2 : xa2,
                   y3 = u ? xb3 : xa3, y4 = u ? xb4 : xa4;
            int p0 = pk16(y0.x, y0.y), p1 = pk16(y1.x, y1.y), p2 = pk16(y2.x, y2.y),
                p3 = pk16(y3.x, y3.y), p4 = pk16(y4.x, y4.y);
            half8 xf = frag4(q0 ? p0 : (q1 ? p4 : 0),
                             q0 ? p1 : 0, q0 ? p2 : 0, q0 ? p3 : 0);

            // refill this set from t+2+u (distance-2 prefetch)
            if (t + 2 + u < T_SZ) {
                const float* xr = xrow + (t + 2 + u) * I_SZ;
                if (u == 0) {
                    xa0 = *(const float2*)(xr + 0); xa1 = *(const float2*)(xr + 2);
                    xa2 = *(const float2*)(xr + 4); xa3 = *(const float2*)(xr + 6);
                    xa4 = *(const float2*)(xr + 8);
                } else {
                    xb0 = *(const float2*)(xr + 0); xb1 = *(const float2*)(xr + 2);
                    xb2 = *(const float2*)(xr + 4); xb3 = *(const float2*)(xr + 6);
                    xb4 = *(const float2*)(xr + 8);
                }
            }

            // 3-deep MFMA chains: bias -> x-part -> h-hi -> h-lo
            f32x4 a0 = MFMAH(xf, frag4(bi0[0], bi0[1], bi0[2], bi0[3]), biasv0);
            f32x4 a1 = MFMAH(xf, frag4(bi1[0], bi1[1], bi1[2], bi1[3]), biasv1);
            half8 hhi = fragv(hhi_), hlo = fragv(hlo_);
            a0 = MFMAH(hhi, frag4(bh0[0], bh0[1], bh0[2], bh0[3]), a0);
            a1 = MFMAH(hhi, frag4(bh1[0], bh1[1], bh1[2], bh1[3]), a1);
            a0 = MFMAH(hlo, frag4(bh0[0], bh0[1], bh0[2], bh0[3]), a0);
            a1 = MFMAH(hlo, frag4(bh1[0], bh1[1], bh1[2], bh1[3]), a1);

            // activations + state (batch = 4*quad + r; quads 2,3 ghost)
            #pragma unroll
            for (int r = 0; r < 4; ++r) {
                float& cs = (r == 0) ? c0 : (r == 1) ? c1 : (r == 2) ? c2 : c3;
                float s0 = __builtin_amdgcn_rcpf(1.0f + __builtin_amdgcn_exp2f(nL * a0[r]));
                float rr = __builtin_amdgcn_rcpf(1.0f + __builtin_amdgcn_exp2f(m1 * a1[r]));
                float s1 = fmaf(sc, rr, so);
                float fg = dpp_ror8(s0);
                float og = dpp_ror8(s1);
                float cn = fmaf(fg, cs, s0 * s1);
                cs = cn;
                float tr = __builtin_amdgcn_rcpf(1.0f + __builtin_amdgcn_exp2f(-2.8853901f * cn));
                float h  = fmaf(og + og, tr, -og);       // o * tanh(c)
                if (wr) {
                    _Float16 hh = (_Float16)h;           // RTN split; pair sums to ~fp32 h
                    _Float16 hl = (_Float16)(h - (float)hh);
                    const int wo = (4 * quad + r) * HSTR + hid;
                    sh_hi[wb][wo] = hh;
                    sh_lo[wb][wo] = hl;
                }
            }
            __syncthreads();
        }
    }

    // ---- dense head: final h in buffer 0 (T even) ----
    if (ws == 0 && lane < 8) {
        float acc = b_dense[0];
        #pragma unroll 4
        for (int j = 0; j < H_SZ; ++j) {
            float hv = (float)sh_hi[0][lane * HSTR + j] + (float)sh_lo[0][lane * HSTR + j];
            acc += hv * W_dense[j];
        }
        out[bbase + lane] = acc;
    }
}

extern "C" void kernel_launch(void* const* d_in, const int* in_sizes, int n_in,
                              void* d_out, int out_size, void* d_ws, size_t ws_size,
                              hipStream_t stream) {
    const float* x       = (const float*)d_in[0];
    const float* W_ih    = (const float*)d_in[1];
    const float* W_hh    = (const float*)d_in[2];
    const float* b_ih    = (const float*)d_in[3];
    const float* b_hh    = (const float*)d_in[4];
    const float* W_dense = (const float*)d_in[5];
    const float* b_dense = (const float*)d_in[6];
    float* out = (float*)d_out;

    // 512 blocks x 4 waves, 8 batches/block -> 2 independent blocks/CU
    lstm_mfma<<<dim3(512), dim3(256), 0, stream>>>(
        x, W_ih, W_hh, b_ih, b_hh, W_dense, b_dense, out);
}

// Round 8
// 363.827 us; speedup vs baseline: 1.2800x; 1.2394x over previous
//
#include <hip/hip_runtime.h>

// LSTM, barrier-free per-wave MFMA formulation. Round 8.
// B=4096, T=512, I=10, H=32, O=1. Gates i,f,g,o.
//
// R7 analysis: 565 VALU-issue cyc/wave/step, half of it ghost-row activation
// work, plus a per-step __syncthreads coupling 4 waves. R8 removes BOTH:
// each wave owns 2 whole batches and all 8 gate-tiles (128 gate-rows / 16
// N-cols), with each batch duplicated across 8 A-rows (rows 0-7 = batch 0,
// rows 8-15 = batch 1). The wave computes its batches' full LSTM step
// locally; h round-trips through a private per-wave LDS buffer (wave-ordered
// DS => NO barriers, NO inter-wave coupling, ever).
//
// Dense activation mapping: lane (Q=lane>>4, L=lane&15) handles exactly one
// (batch, hidden) pair: batch = Q>>1, hid = L + 16*(Q&1). All four gates
// land in-lane (no DPP), using C reg 0 only (C rows 4Q..4Q+3 are duplicates
// of batch Q>>1). 10 transcendentals/lane/step = the dense lower bound.
//
// Tiles: tau = 2*gate + hhalf covers W rows 32*gate + 16*hhalf + n.
// Per step per tile: 3 MFMAs (x_hat*Wih + h_hi*Whh + h_lo*Whh), fp32 C.
// fp16 2-term h split (verified R7, absmax 2e-3); bias folded into the
// sigmoid's fma (mb = scale*bias), so C-init is zero.
//
// A layout: A[m=lane&15][k=Q*8+j]; B: B[k=Q*8+j][n=lane&15]; C: col=lane&15,
// row=4Q+reg (all verified R3-R7).
//
// Grid: 2048 blocks x 64 threads (1 wave/block), 2 batches/wave,
// launch_bounds(64,2) -> 2 waves/SIMD, VGPR cap 256 (plenty).

#define T_SZ 512
#define I_SZ 10
#define H_SZ 32

typedef _Float16 half8  __attribute__((ext_vector_type(8)));
typedef __fp16   fp16x2 __attribute__((ext_vector_type(2)));
typedef float    f32x4  __attribute__((ext_vector_type(4)));
typedef int      i32x4  __attribute__((ext_vector_type(4)));

union FH { i32x4 i; half8 h; };
static __device__ __forceinline__ half8 fragv(i32x4 v) { FH u; u.i = v; return u.h; }
static __device__ __forceinline__ half8 frag4(int a, int b, int c, int d) {
    FH u; u.i = (i32x4){a, b, c, d}; return u.h;
}

// pack 2 fp32 -> 2 fp16 in one dword (v_cvt_pkrtz_f16_f32): low = lo, high = hi
static __device__ __forceinline__ int pk16(float lo, float hi) {
    union { fp16x2 h; int i; } u;
    u.h = __builtin_amdgcn_cvt_pkrtz(lo, hi);
    return u.i;
}

#define MFMAH(A, B, C) __builtin_amdgcn_mfma_f32_16x16x32_f16((A), (B), (C), 0, 0, 0)

__global__ __launch_bounds__(64, 2)
void lstm_wave(const float* __restrict__ x, const float* __restrict__ W_ih,
               const float* __restrict__ W_hh, const float* __restrict__ b_ih,
               const float* __restrict__ b_hh, const float* __restrict__ W_dense,
               const float* __restrict__ b_dense, float* __restrict__ out)
{
    const int lane  = threadIdx.x;        // 0..63 (block = one wave)
    const int L     = lane & 15;          // A m-row / C col
    const int Q     = lane >> 4;          // k-quad
    const int bbase = blockIdx.x * 2;     // 2048 blocks x 2 batches

    const int bA   = L >> 3;              // A-side batch (rows 0-7 -> 0, 8-15 -> 1)
    const int bAct = Q >> 1;              // activation-side batch
    const int hidA = L + 16 * (Q & 1);    // activation-side hidden index

    // ---- B-fragments for all 8 tiles (one-time) ----
    // tile tau = 2*gate + hhalf: W row = 32*gate + 16*hhalf + L
    int bhh[8][4];
    int bih[8][4];
    #pragma unroll
    for (int tau = 0; tau < 8; ++tau) {
        const int wr = 32 * (tau >> 1) + 16 * (tau & 1) + L;
        const float* ph = W_hh + wr * H_SZ + 8 * Q;
        #pragma unroll
        for (int d = 0; d < 4; ++d) {
            float2 v = *(const float2*)(ph + 2 * d);
            bhh[tau][d] = pk16(v.x, v.y);
        }
        bih[tau][0] = 0; bih[tau][1] = 0; bih[tau][2] = 0; bih[tau][3] = 0;
        if (Q == 0) {
            const float* pi = W_ih + wr * I_SZ;
            #pragma unroll
            for (int d = 0; d < 4; ++d) {
                float2 v = *(const float2*)(pi + 2 * d);
                bih[tau][d] = pk16(v.x, v.y);
            }
        } else if (Q == 1) {
            float2 v = *(const float2*)(W_ih + wr * I_SZ + 8);
            bih[tau][0] = pk16(v.x, v.y);
        }
    }

    // ---- biases folded into sigmoid fma: arg = scale*v + scale*bias ----
    const float nL = -1.4426950f;     // -log2(e)       (sigmoid)
    const float m2 = -2.8853901f;     // -2*log2(e)     (tanh via 2*sig(2x)-1)
    const float mbi = nL * (b_ih[hidA]          + b_hh[hidA]);
    const float mbf = nL * (b_ih[32 + hidA]     + b_hh[32 + hidA]);
    const float mbg = m2 * (b_ih[64 + hidA]     + b_hh[64 + hidA]);
    const float mbo = nL * (b_ih[96 + hidA]     + b_hh[96 + hidA]);

    // ---- per-wave LDS h buffer: [buf][plane hi/lo][batch][hid] fp16 ----
    __shared__ __attribute__((aligned(16))) _Float16 hbuf[2][2][2][H_SZ];  // 512 B
    {
        int* zz = (int*)&hbuf[0][0][0][0];
        zz[lane] = 0;                 // 128 ints total
        zz[lane + 64] = 0;
    }
    // wave-ordered DS: zeros visible to this wave's later reads, no barrier.

    // ---- x stream: 2-deep prefetch ----
    const float* xrow = x + (size_t)(bbase + bA) * (T_SZ * I_SZ);
    float2 xa0 = *(const float2*)(xrow + 0), xa1 = *(const float2*)(xrow + 2),
           xa2 = *(const float2*)(xrow + 4), xa3 = *(const float2*)(xrow + 6),
           xa4 = *(const float2*)(xrow + 8);
    float2 xb0 = *(const float2*)(xrow + I_SZ + 0), xb1 = *(const float2*)(xrow + I_SZ + 2),
           xb2 = *(const float2*)(xrow + I_SZ + 4), xb3 = *(const float2*)(xrow + I_SZ + 6),
           xb4 = *(const float2*)(xrow + I_SZ + 8);

    const f32x4 zerov = {0.f, 0.f, 0.f, 0.f};
    float cst = 0.0f;
    float hlast = 0.0f;
    const bool q0 = (Q == 0), q1 = (Q == 1);

    for (int t = 0; t < T_SZ; t += 2) {
        #pragma unroll
        for (int u = 0; u < 2; ++u) {
            const int rb = u, wb = u ^ 1;

            // h fragments from private LDS (A-frag order, broadcast reads)
            const _Float16* hp = &hbuf[rb][0][bA][8 * Q];
            const _Float16* lp = &hbuf[rb][1][bA][8 * Q];
            i32x4 hhi_ = *(const i32x4*)hp;
            i32x4 hlo_ = *(const i32x4*)lp;

            // x_hat A-frag (Q0: k0-7, Q1: k8,9, Q2/3: zero)
            float2 y0 = u ? xb0 : xa0, y1 = u ? xb1 : xa1, y2 = u ? xb2 : xa2,
                   y3 = u ? xb3 : xa3, y4 = u ? xb4 : xa4;
            int p0 = pk16(y0.x, y0.y), p1 = pk16(y1.x, y1.y), p2 = pk16(y2.x, y2.y),
                p3 = pk16(y3.x, y3.y), p4 = pk16(y4.x, y4.y);
            half8 xf = frag4(q0 ? p0 : (q1 ? p4 : 0),
                             q0 ? p1 : 0, q0 ? p2 : 0, q0 ? p3 : 0);

            // refill consumed set from t+2+u (distance-2 prefetch)
            if (t + 2 + u < T_SZ) {
                const float* xr = xrow + (t + 2 + u) * I_SZ;
                if (u == 0) {
                    xa0 = *(const float2*)(xr + 0); xa1 = *(const float2*)(xr + 2);
                    xa2 = *(const float2*)(xr + 4); xa3 = *(const float2*)(xr + 6);
                    xa4 = *(const float2*)(xr + 8);
                } else {
                    xb0 = *(const float2*)(xr + 0); xb1 = *(const float2*)(xr + 2);
                    xb2 = *(const float2*)(xr + 4); xb3 = *(const float2*)(xr + 6);
                    xb4 = *(const float2*)(xr + 8);
                }
            }

            // 8 independent 3-deep MFMA chains; keep only C reg 0 of each
            half8 hhi = fragv(hhi_), hlo = fragv(hlo_);
            float v[8];
            #pragma unroll
            for (int tau = 0; tau < 8; ++tau) {
                f32x4 acc = MFMAH(xf, frag4(bih[tau][0], bih[tau][1], bih[tau][2], bih[tau][3]), zerov);
                acc = MFMAH(hhi, frag4(bhh[tau][0], bhh[tau][1], bhh[tau][2], bhh[tau][3]), acc);
                acc = MFMAH(hlo, frag4(bhh[tau][0], bhh[tau][1], bhh[tau][2], bhh[tau][3]), acc);
                v[tau] = acc[0];
            }

            // dense activations: this lane's (batch bAct, hidden hidA)
            const bool qh = (Q & 1);
            float vi = qh ? v[1] : v[0];
            float vf = qh ? v[3] : v[2];
            float vg = qh ? v[5] : v[4];
            float vo = qh ? v[7] : v[6];
            float ig = __builtin_amdgcn_rcpf(1.0f + __builtin_amdgcn_exp2f(fmaf(nL, vi, mbi)));
            float fg = __builtin_amdgcn_rcpf(1.0f + __builtin_amdgcn_exp2f(fmaf(nL, vf, mbf)));
            float gr = __builtin_amdgcn_rcpf(1.0f + __builtin_amdgcn_exp2f(fmaf(m2, vg, mbg)));
            float gg = fmaf(2.0f, gr, -1.0f);
            float og = __builtin_amdgcn_rcpf(1.0f + __builtin_amdgcn_exp2f(fmaf(nL, vo, mbo)));
            cst = fmaf(fg, cst, ig * gg);
            float tr = __builtin_amdgcn_rcpf(1.0f + __builtin_amdgcn_exp2f(m2 * cst));
            float th = fmaf(2.0f, tr, -1.0f);
            float h  = og * th;
            hlast = h;

            // h write-back, fp16 2-term split, A-frag-order planes
            _Float16 hh = (_Float16)h;
            _Float16 hl = (_Float16)(h - (float)hh);
            hbuf[wb][0][bAct][hidA] = hh;
            hbuf[wb][1][bAct][hidA] = hl;
            // wave-ordered DS: next iteration's reads see these writes.
        }
    }

    // ---- dense head: out[b] = h . W_dense + b_dense ----
    // batch 0 lives in lanes 0-31 (Q=0,1), batch 1 in lanes 32-63 (Q=2,3)
    float v = hlast * W_dense[hidA];
    #pragma unroll
    for (int m = 16; m >= 1; m >>= 1)
        v += __shfl_xor(v, m);            // reduce within 32-lane halves
    if (lane == 0)  out[bbase + 0] = v + b_dense[0];
    if (lane == 32) out[bbase + 1] = v + b_dense[0];
}

extern "C" void kernel_launch(void* const* d_in, const int* in_sizes, int n_in,
                              void* d_out, int out_size, void* d_ws, size_t ws_size,
                              hipStream_t stream) {
    const float* x       = (const float*)d_in[0];
    const float* W_ih    = (const float*)d_in[1];
    const float* W_hh    = (const float*)d_in[2];
    const float* b_ih    = (const float*)d_in[3];
    const float* b_hh    = (const float*)d_in[4];
    const float* W_dense = (const float*)d_in[5];
    const float* b_dense = (const float*)d_in[6];
    float* out = (float*)d_out;

    // 2048 blocks x 64 threads = 2048 independent waves (2/SIMD), 2 batches each
    lstm_wave<<<dim3(2048), dim3(64), 0, stream>>>(
        x, W_ih, W_hh, b_ih, b_hh, W_dense, b_dense, out);
}